// Round 3
// baseline (373.715 us; speedup 1.0000x reference)
//
#include <hip/hip_runtime.h>
#include <hip/hip_bf16.h>

// Problem constants
#define M_DIM 2048
#define K_DIM 50000
#define N_DIM 256
#define L_PATH 32
// GEMM tiling
#define BMt 128
#define BNt 256
#define BKt 64
#define TOTAL_KSTEPS 782      // ceil(50000/64)
#define KSPLIT 16
#define STEPS_PER_SPLIT 49    // ceil(782/16)
#define MTILES 16             // 2048/128

typedef __bf16 bf16x8 __attribute__((ext_vector_type(8)));
typedef __bf16 bf16x4 __attribute__((ext_vector_type(4)));
typedef float f32x4 __attribute__((ext_vector_type(4)));
typedef float fx4 __attribute__((ext_vector_type(4)));

struct StageRegs { fx4 a[4]; fx4 w[8]; };

// x = A (2048x50000) * W^T (W is 256x50000), split-K. bf16 MFMA, fp32 acc.
// T3/T4-lite pipeline: raw s_barrier + counted vmcnt (loads stay in flight
// across the barrier). Per step:
//   issue(t+2 -> free regs); compute(LDS[p]); pack(inflight regs -> LDS[p^1]);
//   s_waitcnt lgkmcnt(0); s_barrier.
__global__ __launch_bounds__(512, 2)
void gemm_bf16_splitk(const float* __restrict__ A, const float* __restrict__ W,
                      float* __restrict__ outp, int use_atomic)
{
  // Swizzled LDS tiles: element (row, col) stored at row*BKt + XOR on 8-col granule
  __shared__ __align__(16) unsigned short sA[2][BMt * BKt];   // 2 x 16 KB
  __shared__ __align__(16) unsigned short sW[2][BNt * BKt];   // 2 x 32 KB

  // XCD-bijective block swizzle (gridDim.x = 256, divisible by 8).
  int bid = blockIdx.x;
  int per = gridDim.x >> 3;
  int Lw = (bid & 7) * per + (bid >> 3);
  int mtile = Lw & (MTILES - 1);
  int ksp = Lw >> 4;                 // MTILES == 16

  int m0 = mtile * BMt;
  int s0 = ksp * STEPS_PER_SPLIT;
  int s1 = s0 + STEPS_PER_SPLIT;
  if (s1 > TOTAL_KSTEPS) s1 = TOTAL_KSTEPS;

  int tid = threadIdx.x;
  int wid = tid >> 6, lane = tid & 63;
  int wm = wid >> 2, wn = wid & 3;          // wave grid 2 x 4, each wave 64x64
  int l15 = lane & 15, l4 = lane >> 4;

  // Coalesced staging: 16 lanes x 16B cover one 64-col row chunk (256 B);
  // per load instruction a wave reads 4 full contiguous rows (1 KB).
  int rowt = tid >> 4;   // 0..31
  int chk  = tid & 15;   // 16B chunk within row (4 fp32 cols)
  const float* Ab = A + (size_t)(m0 + rowt) * K_DIM + chk * 4;
  const float* Wb = W + (size_t)rowt * K_DIM + chk * 4;

  // Per-i LDS write offsets (element index): cols [chk*4, chk*4+4) at swizzled granule
  int offA[4], offW[8];
#pragma unroll
  for (int i = 0; i < 4; ++i) {
    int r = i * 32 + rowt;
    offA[i] = r * BKt + ((((chk >> 1) ^ (r & 7)) << 3) + (chk & 1) * 4);
  }
#pragma unroll
  for (int i = 0; i < 8; ++i) {
    int r = i * 32 + rowt;
    offW[i] = r * BKt + ((((chk >> 1) ^ (r & 7)) << 3) + (chk & 1) * 4);
  }

  StageRegs r0, r1;

  auto issue = [&](StageRegs& R, int s) {
    size_t kb = (size_t)s * BKt;
    const float* ap = Ab + kb;
    const float* wp = Wb + kb;
    int k = s * BKt + chk * 4;
    if (k + 4 <= K_DIM) {
#pragma unroll
      for (int i = 0; i < 4; ++i) R.a[i] = *reinterpret_cast<const fx4*>(ap + (size_t)i * 32 * K_DIM);
#pragma unroll
      for (int i = 0; i < 8; ++i) R.w[i] = *reinterpret_cast<const fx4*>(wp + (size_t)i * 32 * K_DIM);
    } else {
#pragma unroll
      for (int i = 0; i < 4; ++i) {
        fx4 f;
#pragma unroll
        for (int e = 0; e < 4; ++e) f[e] = (k + e < K_DIM) ? ap[(size_t)i * 32 * K_DIM + e] : 0.f;
        R.a[i] = f;
      }
#pragma unroll
      for (int i = 0; i < 8; ++i) {
        fx4 f;
#pragma unroll
        for (int e = 0; e < 4; ++e) f[e] = (k + e < K_DIM) ? wp[(size_t)i * 32 * K_DIM + e] : 0.f;
        R.w[i] = f;
      }
    }
  };

  // fp32 -> bf16 via casts so the compiler emits v_cvt_pk_bf16_f32 (RTNE).
  auto pack = [&](StageRegs& R, int p) {
#pragma unroll
    for (int i = 0; i < 4; ++i) {
      bf16x4 h;
      h[0] = (__bf16)R.a[i][0]; h[1] = (__bf16)R.a[i][1];
      h[2] = (__bf16)R.a[i][2]; h[3] = (__bf16)R.a[i][3];
      *reinterpret_cast<bf16x4*>(&sA[p][offA[i]]) = h;
    }
#pragma unroll
    for (int i = 0; i < 8; ++i) {
      bf16x4 h;
      h[0] = (__bf16)R.w[i][0]; h[1] = (__bf16)R.w[i][1];
      h[2] = (__bf16)R.w[i][2]; h[3] = (__bf16)R.w[i][3];
      *reinterpret_cast<bf16x4*>(&sW[p][offW[i]]) = h;
    }
  };

  f32x4 acc[4][4] = {};

  auto compute = [&](int p) {
#pragma unroll
    for (int kk = 0; kk < 2; ++kk) {
      bf16x8 afr[4], bfr[4];
      int c = kk * 32 + l4 * 8;
#pragma unroll
      for (int mf = 0; mf < 4; ++mf) {
        int r = wm * 64 + mf * 16 + l15;
        afr[mf] = *reinterpret_cast<const bf16x8*>(&sA[p][r * BKt + (c ^ ((r & 7) << 3))]);
      }
#pragma unroll
      for (int nf = 0; nf < 4; ++nf) {
        int r = wn * 64 + nf * 16 + l15;
        bfr[nf] = *reinterpret_cast<const bf16x8*>(&sW[p][r * BKt + (c ^ ((r & 7) << 3))]);
      }
#pragma unroll
      for (int mf = 0; mf < 4; ++mf)
#pragma unroll
        for (int nf = 0; nf < 4; ++nf)
          acc[mf][nf] = __builtin_amdgcn_mfma_f32_16x16x32_bf16(afr[mf], bfr[nf], acc[mf][nf], 0, 0, 0);
    }
  };

#define WB() do { asm volatile("s_waitcnt lgkmcnt(0)" ::: "memory"); \
                  __builtin_amdgcn_s_barrier(); } while (0)

  // Prologue: tile s0 -> regs r0; tile s0+1 loads in flight (r1); pack s0 to LDS[0].
  issue(r0, s0);
  if (s0 + 1 < s1) issue(r1, s0 + 1);
  pack(r0, 0);           // counted vmcnt: waits r0 only, r1 stays in flight
  WB();

  int t = s0, p = 0;
  for (;;) {
    // phase A: inflight = r1 (tile t+1), free = r0
    if (t + 1 >= s1) { compute(p); break; }
    if (t + 2 < s1) issue(r0, t + 2);
    compute(p);
    pack(r1, p ^ 1);     // counted vmcnt: r0's loads survive the barrier
    WB();
    ++t; p ^= 1;
    // phase B: inflight = r0, free = r1
    if (t + 1 >= s1) { compute(p); break; }
    if (t + 2 < s1) issue(r1, t + 2);
    compute(p);
    pack(r0, p ^ 1);
    WB();
    ++t; p ^= 1;
  }
#undef WB

  // epilogue: C/D layout col = lane&15, row = (lane>>4)*4 + j
  if (use_atomic) {
#pragma unroll
    for (int mf = 0; mf < 4; ++mf)
#pragma unroll
      for (int nf = 0; nf < 4; ++nf)
#pragma unroll
        for (int j = 0; j < 4; ++j) {
          int row = m0 + wm * 64 + mf * 16 + l4 * 4 + j;
          int col = wn * 64 + nf * 16 + l15;
          atomicAdd(&outp[(size_t)row * N_DIM + col], acc[mf][nf][j]);
        }
  } else {
    float* part = outp + (size_t)ksp * (M_DIM * N_DIM);
#pragma unroll
    for (int mf = 0; mf < 4; ++mf)
#pragma unroll
      for (int nf = 0; nf < 4; ++nf)
#pragma unroll
        for (int j = 0; j < 4; ++j) {
          int row = m0 + wm * 64 + mf * 16 + l4 * 4 + j;
          int col = wn * 64 + nf * 16 + l15;
          part[(size_t)row * N_DIM + col] = acc[mf][nf][j];
        }
  }
}

// One block (256 thr = 4 waves) per sample: reduce split-K partials for this row
// into LDS, gather path vecs, dot with x, BCE.
__global__ __launch_bounds__(256)
void loss_kernel(const float* __restrict__ part, int nparts,
                 const float* __restrict__ cls_w,
                 const int* __restrict__ nodes, const int* __restrict__ codes,
                 const int* __restrict__ lens, float* __restrict__ per_sample)
{
  int i = blockIdx.x;
  int tid = threadIdx.x;
  __shared__ float s_x[N_DIM];
  {
    float s = 0.f;
    for (int k = 0; k < nparts; ++k)
      s += part[(size_t)k * (M_DIM * N_DIM) + (size_t)i * N_DIM + tid];
    s_x[tid] = s;
  }
  __syncthreads();

  int wid = tid >> 6, lane = tid & 63;
  __shared__ float s_logit[L_PATH];
  fx4 xv = *reinterpret_cast<const fx4*>(&s_x[lane * 4]);
#pragma unroll
  for (int j = 0; j < 8; ++j) {
    int pos = wid * 8 + j;
    int node = nodes[i * L_PATH + pos];
    fx4 cv = *reinterpret_cast<const fx4*>(&cls_w[(size_t)node * N_DIM + lane * 4]);
    float d = xv[0] * cv[0] + xv[1] * cv[1] + xv[2] * cv[2] + xv[3] * cv[3];
#pragma unroll
    for (int s = 32; s > 0; s >>= 1) d += __shfl_xor(d, s);
    if (lane == 0) s_logit[pos] = d;
  }
  __syncthreads();
  if (wid == 0) {
    int len = lens[i];
    int lenc = len < 1 ? 1 : len;
    float v = 0.f;
    if (lane < L_PATH && lane < lenc) {
      float z = s_logit[lane];
      float y = (float)codes[i * L_PATH + lane];
      v = fmaxf(z, 0.f) - z * y + log1pf(expf(-fabsf(z)));
    }
#pragma unroll
    for (int s = 32; s > 0; s >>= 1) v += __shfl_xor(v, s);
    if (lane == 0) per_sample[i] = v / (float)lenc;
  }
}

__global__ __launch_bounds__(256)
void final_reduce(const float* __restrict__ ps, float* __restrict__ out) {
  int tid = threadIdx.x;
  float s = 0.f;
#pragma unroll
  for (int i = 0; i < M_DIM / 256; ++i) s += ps[tid + i * 256];
  __shared__ float sm[4];
#pragma unroll
  for (int sh = 32; sh > 0; sh >>= 1) s += __shfl_xor(s, sh);
  if ((tid & 63) == 0) sm[tid >> 6] = s;
  __syncthreads();
  if (tid == 0) out[0] = (sm[0] + sm[1] + sm[2] + sm[3]) * (1.0f / (float)M_DIM);
}

extern "C" void kernel_launch(void* const* d_in, const int* in_sizes, int n_in,
                              void* d_out, int out_size, void* d_ws, size_t ws_size,
                              hipStream_t stream) {
  const float* A     = (const float*)d_in[0];   // inputs_vector [2048, 50000]
  const float* W     = (const float*)d_in[1];   // W [256, 50000]
  const float* cls_w = (const float*)d_in[2];   // [49999, 256]
  const int* nodes   = (const int*)d_in[3];     // [2048, 32]
  const int* codes   = (const int*)d_in[4];     // [2048, 32]
  const int* lens    = (const int*)d_in[5];     // [2048]
  float* out = (float*)d_out;

  char* ws = (char*)d_ws;
  const size_t XBYTES = (size_t)M_DIM * N_DIM * sizeof(float);   // 2 MB
  float* per_sample = (float*)ws;                                // 8 KB
  float* x          = (float*)(ws + (size_t)(64u << 10));        // 2 MB (atomic path)
  float* partials   = (float*)(ws + (size_t)(4u << 20));         // KSPLIT * 2 MB

  int use_atomic = (ws_size < (size_t)(4u << 20) + (size_t)KSPLIT * XBYTES) ? 1 : 0;

  if (use_atomic) {
    hipMemsetAsync(x, 0, XBYTES, stream);
    gemm_bf16_splitk<<<dim3(MTILES * KSPLIT), dim3(512), 0, stream>>>(A, W, x, 1);
    loss_kernel<<<dim3(M_DIM), dim3(256), 0, stream>>>(x, 1, cls_w, nodes, codes, lens, per_sample);
  } else {
    gemm_bf16_splitk<<<dim3(MTILES * KSPLIT), dim3(512), 0, stream>>>(A, W, partials, 0);
    loss_kernel<<<dim3(M_DIM), dim3(256), 0, stream>>>(partials, KSPLIT, cls_w, nodes, codes, lens, per_sample);
  }
  final_reduce<<<dim3(1), dim3(256), 0, stream>>>(per_sample, out);
}

// Round 4
// 371.426 us; speedup vs baseline: 1.0062x; 1.0062x over previous
//
#include <hip/hip_runtime.h>
#include <hip/hip_bf16.h>

// Problem constants
#define M_DIM 2048
#define K_DIM 50000
#define N_DIM 256
#define L_PATH 32
// GEMM tiling
#define BMt 128
#define BNt 256
#define BKt 64
#define TOTAL_KSTEPS 782      // ceil(50000/64)
#define KSPLIT 16
#define STEPS_PER_SPLIT 49    // ceil(782/16)
#define MTILES 16             // 2048/128

typedef __bf16 bf16x8 __attribute__((ext_vector_type(8)));
typedef __bf16 bf16x4 __attribute__((ext_vector_type(4)));
typedef float f32x4 __attribute__((ext_vector_type(4)));
typedef float fx4 __attribute__((ext_vector_type(4)));

struct StageRegs { fx4 a[4]; fx4 w[8]; };

// x = A (2048x50000) * W^T (W is 256x50000), split-K. bf16 MFMA, fp32 acc.
// T3/T4-lite pipeline: raw s_barrier + counted vmcnt (loads stay in flight
// across the barrier). Per step:
//   issue(t+2 -> free regs); compute(LDS[p]); pack(inflight regs -> LDS[p^1]);
//   s_waitcnt lgkmcnt(0); s_barrier.
// NOTE: no min-waves arg in launch_bounds — R3's (512,2) pinned VGPR=128 and
// spilled the stage registers (582 MB scratch writes, 2.3x slowdown).
__global__ __launch_bounds__(512)
void gemm_bf16_splitk(const float* __restrict__ A, const float* __restrict__ W,
                      float* __restrict__ outp, int use_atomic)
{
  // Swizzled LDS tiles: element (row, col) stored at row*BKt + XOR on 8-col granule
  __shared__ __align__(16) unsigned short sA[2][BMt * BKt];   // 2 x 16 KB
  __shared__ __align__(16) unsigned short sW[2][BNt * BKt];   // 2 x 32 KB

  // XCD-bijective block swizzle (gridDim.x = 256, divisible by 8).
  int bid = blockIdx.x;
  int per = gridDim.x >> 3;
  int Lw = (bid & 7) * per + (bid >> 3);
  int mtile = Lw & (MTILES - 1);
  int ksp = Lw >> 4;                 // MTILES == 16

  int m0 = mtile * BMt;
  int s0 = ksp * STEPS_PER_SPLIT;
  int s1 = s0 + STEPS_PER_SPLIT;
  if (s1 > TOTAL_KSTEPS) s1 = TOTAL_KSTEPS;

  int tid = threadIdx.x;
  int wid = tid >> 6, lane = tid & 63;
  int wm = wid >> 2, wn = wid & 3;          // wave grid 2 x 4, each wave 64x64
  int l15 = lane & 15, l4 = lane >> 4;

  // Coalesced staging: 16 lanes x 16B cover one 64-col row chunk (256 B);
  // per load instruction a wave reads 4 full contiguous rows (1 KB).
  int rowt = tid >> 4;   // 0..31
  int chk  = tid & 15;   // 16B chunk within row (4 fp32 cols)
  const float* Ab = A + (size_t)(m0 + rowt) * K_DIM + chk * 4;
  const float* Wb = W + (size_t)rowt * K_DIM + chk * 4;

  // Per-i LDS write offsets (element index): cols [chk*4, chk*4+4) at swizzled granule
  int offA[4], offW[8];
#pragma unroll
  for (int i = 0; i < 4; ++i) {
    int r = i * 32 + rowt;
    offA[i] = r * BKt + ((((chk >> 1) ^ (r & 7)) << 3) + (chk & 1) * 4);
  }
#pragma unroll
  for (int i = 0; i < 8; ++i) {
    int r = i * 32 + rowt;
    offW[i] = r * BKt + ((((chk >> 1) ^ (r & 7)) << 3) + (chk & 1) * 4);
  }

  StageRegs r0, r1;

  auto issue = [&](StageRegs& R, int s) {
    size_t kb = (size_t)s * BKt;
    const float* ap = Ab + kb;
    const float* wp = Wb + kb;
    int k = s * BKt + chk * 4;
    if (k + 4 <= K_DIM) {
#pragma unroll
      for (int i = 0; i < 4; ++i) R.a[i] = *reinterpret_cast<const fx4*>(ap + (size_t)i * 32 * K_DIM);
#pragma unroll
      for (int i = 0; i < 8; ++i) R.w[i] = *reinterpret_cast<const fx4*>(wp + (size_t)i * 32 * K_DIM);
    } else {
#pragma unroll
      for (int i = 0; i < 4; ++i) {
        fx4 f;
#pragma unroll
        for (int e = 0; e < 4; ++e) f[e] = (k + e < K_DIM) ? ap[(size_t)i * 32 * K_DIM + e] : 0.f;
        R.a[i] = f;
      }
#pragma unroll
      for (int i = 0; i < 8; ++i) {
        fx4 f;
#pragma unroll
        for (int e = 0; e < 4; ++e) f[e] = (k + e < K_DIM) ? wp[(size_t)i * 32 * K_DIM + e] : 0.f;
        R.w[i] = f;
      }
    }
  };

  // fp32 -> bf16 via casts so the compiler emits v_cvt_pk_bf16_f32 (RTNE).
  auto pack = [&](StageRegs& R, int p) {
#pragma unroll
    for (int i = 0; i < 4; ++i) {
      bf16x4 h;
      h[0] = (__bf16)R.a[i][0]; h[1] = (__bf16)R.a[i][1];
      h[2] = (__bf16)R.a[i][2]; h[3] = (__bf16)R.a[i][3];
      *reinterpret_cast<bf16x4*>(&sA[p][offA[i]]) = h;
    }
#pragma unroll
    for (int i = 0; i < 8; ++i) {
      bf16x4 h;
      h[0] = (__bf16)R.w[i][0]; h[1] = (__bf16)R.w[i][1];
      h[2] = (__bf16)R.w[i][2]; h[3] = (__bf16)R.w[i][3];
      *reinterpret_cast<bf16x4*>(&sW[p][offW[i]]) = h;
    }
  };

  f32x4 acc[4][4] = {};

  auto compute = [&](int p) {
#pragma unroll
    for (int kk = 0; kk < 2; ++kk) {
      bf16x8 afr[4], bfr[4];
      int c = kk * 32 + l4 * 8;
#pragma unroll
      for (int mf = 0; mf < 4; ++mf) {
        int r = wm * 64 + mf * 16 + l15;
        afr[mf] = *reinterpret_cast<const bf16x8*>(&sA[p][r * BKt + (c ^ ((r & 7) << 3))]);
      }
#pragma unroll
      for (int nf = 0; nf < 4; ++nf) {
        int r = wn * 64 + nf * 16 + l15;
        bfr[nf] = *reinterpret_cast<const bf16x8*>(&sW[p][r * BKt + (c ^ ((r & 7) << 3))]);
      }
#pragma unroll
      for (int mf = 0; mf < 4; ++mf)
#pragma unroll
        for (int nf = 0; nf < 4; ++nf)
          acc[mf][nf] = __builtin_amdgcn_mfma_f32_16x16x32_bf16(afr[mf], bfr[nf], acc[mf][nf], 0, 0, 0);
    }
  };

#define WB() do { asm volatile("s_waitcnt lgkmcnt(0)" ::: "memory"); \
                  __builtin_amdgcn_s_barrier(); } while (0)

  // Prologue: tile s0 -> regs r0; tile s0+1 loads in flight (r1); pack s0 to LDS[0].
  issue(r0, s0);
  if (s0 + 1 < s1) issue(r1, s0 + 1);
  pack(r0, 0);           // counted vmcnt: waits r0 only, r1 stays in flight
  WB();

  int t = s0, p = 0;
  for (;;) {
    // phase A: inflight = r1 (tile t+1), free = r0
    if (t + 1 >= s1) { compute(p); break; }
    if (t + 2 < s1) issue(r0, t + 2);
    compute(p);
    pack(r1, p ^ 1);     // counted vmcnt: r0's loads survive the barrier
    WB();
    ++t; p ^= 1;
    // phase B: inflight = r0, free = r1
    if (t + 1 >= s1) { compute(p); break; }
    if (t + 2 < s1) issue(r1, t + 2);
    compute(p);
    pack(r0, p ^ 1);
    WB();
    ++t; p ^= 1;
  }
#undef WB

  // epilogue: C/D layout col = lane&15, row = (lane>>4)*4 + j
  if (use_atomic) {
#pragma unroll
    for (int mf = 0; mf < 4; ++mf)
#pragma unroll
      for (int nf = 0; nf < 4; ++nf)
#pragma unroll
        for (int j = 0; j < 4; ++j) {
          int row = m0 + wm * 64 + mf * 16 + l4 * 4 + j;
          int col = wn * 64 + nf * 16 + l15;
          atomicAdd(&outp[(size_t)row * N_DIM + col], acc[mf][nf][j]);
        }
  } else {
    float* part = outp + (size_t)ksp * (M_DIM * N_DIM);
#pragma unroll
    for (int mf = 0; mf < 4; ++mf)
#pragma unroll
      for (int nf = 0; nf < 4; ++nf)
#pragma unroll
        for (int j = 0; j < 4; ++j) {
          int row = m0 + wm * 64 + mf * 16 + l4 * 4 + j;
          int col = wn * 64 + nf * 16 + l15;
          part[(size_t)row * N_DIM + col] = acc[mf][nf][j];
        }
  }
}

// One block (256 thr = 4 waves) per sample: reduce split-K partials for this row
// into LDS, gather path vecs, dot with x, BCE.
__global__ __launch_bounds__(256)
void loss_kernel(const float* __restrict__ part, int nparts,
                 const float* __restrict__ cls_w,
                 const int* __restrict__ nodes, const int* __restrict__ codes,
                 const int* __restrict__ lens, float* __restrict__ per_sample)
{
  int i = blockIdx.x;
  int tid = threadIdx.x;
  __shared__ float s_x[N_DIM];
  {
    float s = 0.f;
    for (int k = 0; k < nparts; ++k)
      s += part[(size_t)k * (M_DIM * N_DIM) + (size_t)i * N_DIM + tid];
    s_x[tid] = s;
  }
  __syncthreads();

  int wid = tid >> 6, lane = tid & 63;
  __shared__ float s_logit[L_PATH];
  fx4 xv = *reinterpret_cast<const fx4*>(&s_x[lane * 4]);
#pragma unroll
  for (int j = 0; j < 8; ++j) {
    int pos = wid * 8 + j;
    int node = nodes[i * L_PATH + pos];
    fx4 cv = *reinterpret_cast<const fx4*>(&cls_w[(size_t)node * N_DIM + lane * 4]);
    float d = xv[0] * cv[0] + xv[1] * cv[1] + xv[2] * cv[2] + xv[3] * cv[3];
#pragma unroll
    for (int s = 32; s > 0; s >>= 1) d += __shfl_xor(d, s);
    if (lane == 0) s_logit[pos] = d;
  }
  __syncthreads();
  if (wid == 0) {
    int len = lens[i];
    int lenc = len < 1 ? 1 : len;
    float v = 0.f;
    if (lane < L_PATH && lane < lenc) {
      float z = s_logit[lane];
      float y = (float)codes[i * L_PATH + lane];
      v = fmaxf(z, 0.f) - z * y + log1pf(expf(-fabsf(z)));
    }
#pragma unroll
    for (int s = 32; s > 0; s >>= 1) v += __shfl_xor(v, s);
    if (lane == 0) per_sample[i] = v / (float)lenc;
  }
}

__global__ __launch_bounds__(256)
void final_reduce(const float* __restrict__ ps, float* __restrict__ out) {
  int tid = threadIdx.x;
  float s = 0.f;
#pragma unroll
  for (int i = 0; i < M_DIM / 256; ++i) s += ps[tid + i * 256];
  __shared__ float sm[4];
#pragma unroll
  for (int sh = 32; sh > 0; sh >>= 1) s += __shfl_xor(s, sh);
  if ((tid & 63) == 0) sm[tid >> 6] = s;
  __syncthreads();
  if (tid == 0) out[0] = (sm[0] + sm[1] + sm[2] + sm[3]) * (1.0f / (float)M_DIM);
}

extern "C" void kernel_launch(void* const* d_in, const int* in_sizes, int n_in,
                              void* d_out, int out_size, void* d_ws, size_t ws_size,
                              hipStream_t stream) {
  const float* A     = (const float*)d_in[0];   // inputs_vector [2048, 50000]
  const float* W     = (const float*)d_in[1];   // W [256, 50000]
  const float* cls_w = (const float*)d_in[2];   // [49999, 256]
  const int* nodes   = (const int*)d_in[3];     // [2048, 32]
  const int* codes   = (const int*)d_in[4];     // [2048, 32]
  const int* lens    = (const int*)d_in[5];     // [2048]
  float* out = (float*)d_out;

  char* ws = (char*)d_ws;
  const size_t XBYTES = (size_t)M_DIM * N_DIM * sizeof(float);   // 2 MB
  float* per_sample = (float*)ws;                                // 8 KB
  float* x          = (float*)(ws + (size_t)(64u << 10));        // 2 MB (atomic path)
  float* partials   = (float*)(ws + (size_t)(4u << 20));         // KSPLIT * 2 MB

  int use_atomic = (ws_size < (size_t)(4u << 20) + (size_t)KSPLIT * XBYTES) ? 1 : 0;

  if (use_atomic) {
    hipMemsetAsync(x, 0, XBYTES, stream);
    gemm_bf16_splitk<<<dim3(MTILES * KSPLIT), dim3(512), 0, stream>>>(A, W, x, 1);
    loss_kernel<<<dim3(M_DIM), dim3(256), 0, stream>>>(x, 1, cls_w, nodes, codes, lens, per_sample);
  } else {
    gemm_bf16_splitk<<<dim3(MTILES * KSPLIT), dim3(512), 0, stream>>>(A, W, partials, 0);
    loss_kernel<<<dim3(M_DIM), dim3(256), 0, stream>>>(partials, KSPLIT, cls_w, nodes, codes, lens, per_sample);
  }
  final_reduce<<<dim3(1), dim3(256), 0, stream>>>(per_sample, out);
}

// Round 5
// 228.029 us; speedup vs baseline: 1.6389x; 1.6289x over previous
//
#include <hip/hip_runtime.h>
#include <hip/hip_bf16.h>

// Problem constants
#define M_DIM 2048
#define K_DIM 50000
#define N_DIM 256
#define L_PATH 32
// GEMM tiling: BM=128, BN=256, BK=32 (fp32 in LDS), triple-buffered
#define BMt 128
#define BNt 256
#define BK 32
#define TOTAL_STEPS 1563      // ceil(50000/32); last step covers k 49984..50015 (16-col tail)
#define KSPLIT 16
#define SPS 98                // ceil(1563/16)
#define MTILES 16             // 2048/128
#define ATILE (BMt * BK)      // 4096 floats = 16KB
#define WTILE (BNt * BK)      // 8192 floats = 32KB

typedef __bf16 bf16x8 __attribute__((ext_vector_type(8)));
typedef float f32x4 __attribute__((ext_vector_type(4)));
typedef float fx4 __attribute__((ext_vector_type(4)));

// global_load_lds: LDS dest = wave-uniform base + lane*16B (linear);
// per-lane global source carries the swizzle (m104/m173 pattern).
#define GLL(g, l) __builtin_amdgcn_global_load_lds(                        \
    (const __attribute__((address_space(1))) void*)(g),                    \
    (__attribute__((address_space(3))) void*)(l), 16, 0, 0)

// x = A (2048x50000) * W^T (W is 256x50000), split-K=16.
// fp32 staged to LDS via global_load_lds (NO stage registers -> no spill;
// R3/R4 showed 548MB of scratch writes from reg-staging at VGPR cap 128).
// fp32 -> bf16 conversion happens on the LDS->reg fragment read.
// Pipeline: 3 LDS buffers, 1 barrier/step, counted vmcnt(6) (2 tiles in flight).
__global__ __launch_bounds__(512)
void gemm_bf16_splitk(const float* __restrict__ A, const float* __restrict__ W,
                      float* __restrict__ outp, int use_atomic)
{
  __shared__ __align__(16) float sA[3 * ATILE];   // 48 KB
  __shared__ __align__(16) float sW[3 * WTILE];   // 96 KB  (total 144 KB)

  // XCD-bijective block swizzle (gridDim.x = 256): same-ksp blocks land on
  // 1-2 XCDs so the shared W chunk stays in those L2s.
  int bid = blockIdx.x;
  int per = gridDim.x >> 3;
  int Lw = (bid & 7) * per + (bid >> 3);
  int mtile = Lw & (MTILES - 1);
  int ksp = Lw >> 4;                 // MTILES == 16

  int m0 = mtile * BMt;
  int s0 = ksp * SPS;
  int s1 = s0 + SPS;
  if (s1 > TOTAL_STEPS) s1 = TOTAL_STEPS;

  int tid = threadIdx.x;
  int wid = tid >> 6, lane = tid & 63;
  int wm = wid >> 2, wn = wid & 3;          // wave grid 2 x 4, each wave 64x64
  int l15 = lane & 15, l4 = lane >> 4;

  // ---- staging geometry ----
  // One GLL call = 1KB = 8 rows x 128B. Lane -> row base+ (lane>>3), granule lane&7.
  // Swizzle: LDS granule g of row r holds global granule g ^ (r&7); since
  // row%8 == lane>>3 here, each lane's source granule gg = (lane&7)^(lane>>3).
  int gg = (lane & 7) ^ (lane >> 3);
  int cA = wid * 2;                  // A calls cA, cA+1 : rows [cA*8, cA*8+16)
  int cW = wid * 4;                  // W calls cW..cW+3 : rows [cW*8, cW*8+32)
  const float* pA0 = A + (size_t)(m0 + cA * 8 + (lane >> 3)) * K_DIM + gg * 4;
  const float* pA1 = pA0 + (size_t)8 * K_DIM;
  const float* pW0 = W + (size_t)(cW * 8 + (lane >> 3)) * K_DIM + gg * 4;
  const float* pW1 = pW0 + (size_t)8 * K_DIM;
  const float* pW2 = pW0 + (size_t)16 * K_DIM;
  const float* pW3 = pW0 + (size_t)24 * K_DIM;
  int lane4 = lane * 4;              // this lane's 16B slot within a 1KB chunk

  auto stage = [&](int p, int s) {
    size_t koff = (size_t)s * BK;
    float* dA = sA + p * ATILE + cA * 256;
    float* dW = sW + p * WTILE + cW * 256;
    if (s != TOTAL_STEPS - 1) {
      GLL(pA0 + koff, dA);
      GLL(pA1 + koff, dA + 256);
      GLL(pW0 + koff, dW);
      GLL(pW1 + koff, dW + 256);
      GLL(pW2 + koff, dW + 512);
      GLL(pW3 + koff, dW + 768);
    } else {
      // tail: only granules 0..3 (16 cols) are in-bounds
      if (gg < 4) {
        GLL(pA0 + koff, dA);
        GLL(pA1 + koff, dA + 256);
        GLL(pW0 + koff, dW);
        GLL(pW1 + koff, dW + 256);
        GLL(pW2 + koff, dW + 512);
        GLL(pW3 + koff, dW + 768);
      } else {
        fx4 z = {0.f, 0.f, 0.f, 0.f};
        *reinterpret_cast<fx4*>(dA + lane4) = z;
        *reinterpret_cast<fx4*>(dA + 256 + lane4) = z;
        *reinterpret_cast<fx4*>(dW + lane4) = z;
        *reinterpret_cast<fx4*>(dW + 256 + lane4) = z;
        *reinterpret_cast<fx4*>(dW + 512 + lane4) = z;
        *reinterpret_cast<fx4*>(dW + 768 + lane4) = z;
        asm volatile("s_waitcnt lgkmcnt(0)" ::: "memory");
      }
    }
  };

  f32x4 acc[4][4] = {};

  // Consumer fragment read: row r, k = l4*8 + e. Granules l4*2, l4*2+1,
  // swizzled by ^(r&7). Uniform 8 touches/bank -> conflict-free for b128.
  auto compute = [&](const float* bufA, const float* bufW) {
    bf16x8 afr[4], bfr[4];
#pragma unroll
    for (int mf = 0; mf < 4; ++mf) {
      int r = wm * 64 + mf * 16 + l15;
      int x7 = r & 7;
      const float* pr = bufA + r * BK;
      fx4 lo = *reinterpret_cast<const fx4*>(pr + (((l4 * 2) ^ x7) * 4));
      fx4 hi = *reinterpret_cast<const fx4*>(pr + (((l4 * 2 + 1) ^ x7) * 4));
      bf16x8 f;
      f[0] = (__bf16)lo[0]; f[1] = (__bf16)lo[1]; f[2] = (__bf16)lo[2]; f[3] = (__bf16)lo[3];
      f[4] = (__bf16)hi[0]; f[5] = (__bf16)hi[1]; f[6] = (__bf16)hi[2]; f[7] = (__bf16)hi[3];
      afr[mf] = f;
    }
#pragma unroll
    for (int nf = 0; nf < 4; ++nf) {
      int r = wn * 64 + nf * 16 + l15;
      int x7 = r & 7;
      const float* pr = bufW + r * BK;
      fx4 lo = *reinterpret_cast<const fx4*>(pr + (((l4 * 2) ^ x7) * 4));
      fx4 hi = *reinterpret_cast<const fx4*>(pr + (((l4 * 2 + 1) ^ x7) * 4));
      bf16x8 f;
      f[0] = (__bf16)lo[0]; f[1] = (__bf16)lo[1]; f[2] = (__bf16)lo[2]; f[3] = (__bf16)lo[3];
      f[4] = (__bf16)hi[0]; f[5] = (__bf16)hi[1]; f[6] = (__bf16)hi[2]; f[7] = (__bf16)hi[3];
      bfr[nf] = f;
    }
#pragma unroll
    for (int mf = 0; mf < 4; ++mf)
#pragma unroll
      for (int nf = 0; nf < 4; ++nf)
        acc[mf][nf] = __builtin_amdgcn_mfma_f32_16x16x32_bf16(afr[mf], bfr[nf], acc[mf][nf], 0, 0, 0);
  };

  // Prologue: tiles s0, s0+1 in flight (12 loads/wave).
  stage(0, s0);
  stage(1, s0 + 1);

  int t = s0, p = 0;
  while (t + 1 < s1) {
    asm volatile("s_waitcnt vmcnt(6)" ::: "memory");   // tile t landed; t+1 in flight
    __builtin_amdgcn_s_barrier();                      // all waves' tile-t writes visible
    asm volatile("" ::: "memory");                     // pin stage/ds_reads below barrier
    if (t + 2 < s1) {
      int p2 = p + 2; if (p2 >= 3) p2 -= 3;
      stage(p2, t + 2);                                // overwrites buf freed at this barrier
    }
    compute(sA + p * ATILE, sW + p * WTILE);
    ++t; ++p; if (p == 3) p = 0;
  }
  asm volatile("s_waitcnt vmcnt(0)" ::: "memory");     // last tile
  __builtin_amdgcn_s_barrier();
  asm volatile("" ::: "memory");
  compute(sA + p * ATILE, sW + p * WTILE);

  // epilogue: C/D layout col = lane&15, row = (lane>>4)*4 + j
  if (use_atomic) {
#pragma unroll
    for (int mf = 0; mf < 4; ++mf)
#pragma unroll
      for (int nf = 0; nf < 4; ++nf)
#pragma unroll
        for (int j = 0; j < 4; ++j) {
          int row = m0 + wm * 64 + mf * 16 + l4 * 4 + j;
          int col = wn * 64 + nf * 16 + l15;
          atomicAdd(&outp[(size_t)row * N_DIM + col], acc[mf][nf][j]);
        }
  } else {
    float* part = outp + (size_t)ksp * (M_DIM * N_DIM);
#pragma unroll
    for (int mf = 0; mf < 4; ++mf)
#pragma unroll
      for (int nf = 0; nf < 4; ++nf)
#pragma unroll
        for (int j = 0; j < 4; ++j) {
          int row = m0 + wm * 64 + mf * 16 + l4 * 4 + j;
          int col = wn * 64 + nf * 16 + l15;
          part[(size_t)row * N_DIM + col] = acc[mf][nf][j];
        }
  }
}

// One block (256 thr = 4 waves) per sample: reduce split-K partials for this row
// into LDS, gather path vecs, dot with x, BCE.
__global__ __launch_bounds__(256)
void loss_kernel(const float* __restrict__ part, int nparts,
                 const float* __restrict__ cls_w,
                 const int* __restrict__ nodes, const int* __restrict__ codes,
                 const int* __restrict__ lens, float* __restrict__ per_sample)
{
  int i = blockIdx.x;
  int tid = threadIdx.x;
  __shared__ float s_x[N_DIM];
  {
    float s = 0.f;
    for (int k = 0; k < nparts; ++k)
      s += part[(size_t)k * (M_DIM * N_DIM) + (size_t)i * N_DIM + tid];
    s_x[tid] = s;
  }
  __syncthreads();

  int wid = tid >> 6, lane = tid & 63;
  __shared__ float s_logit[L_PATH];
  fx4 xv = *reinterpret_cast<const fx4*>(&s_x[lane * 4]);
#pragma unroll
  for (int j = 0; j < 8; ++j) {
    int pos = wid * 8 + j;
    int node = nodes[i * L_PATH + pos];
    fx4 cv = *reinterpret_cast<const fx4*>(&cls_w[(size_t)node * N_DIM + lane * 4]);
    float d = xv[0] * cv[0] + xv[1] * cv[1] + xv[2] * cv[2] + xv[3] * cv[3];
#pragma unroll
    for (int s = 32; s > 0; s >>= 1) d += __shfl_xor(d, s);
    if (lane == 0) s_logit[pos] = d;
  }
  __syncthreads();
  if (wid == 0) {
    int len = lens[i];
    int lenc = len < 1 ? 1 : len;
    float v = 0.f;
    if (lane < L_PATH && lane < lenc) {
      float z = s_logit[lane];
      float y = (float)codes[i * L_PATH + lane];
      v = fmaxf(z, 0.f) - z * y + log1pf(expf(-fabsf(z)));
    }
#pragma unroll
    for (int s = 32; s > 0; s >>= 1) v += __shfl_xor(v, s);
    if (lane == 0) per_sample[i] = v / (float)lenc;
  }
}

__global__ __launch_bounds__(256)
void final_reduce(const float* __restrict__ ps, float* __restrict__ out) {
  int tid = threadIdx.x;
  float s = 0.f;
#pragma unroll
  for (int i = 0; i < M_DIM / 256; ++i) s += ps[tid + i * 256];
  __shared__ float sm[4];
#pragma unroll
  for (int sh = 32; sh > 0; sh >>= 1) s += __shfl_xor(s, sh);
  if ((tid & 63) == 0) sm[tid >> 6] = s;
  __syncthreads();
  if (tid == 0) out[0] = (sm[0] + sm[1] + sm[2] + sm[3]) * (1.0f / (float)M_DIM);
}

extern "C" void kernel_launch(void* const* d_in, const int* in_sizes, int n_in,
                              void* d_out, int out_size, void* d_ws, size_t ws_size,
                              hipStream_t stream) {
  const float* A     = (const float*)d_in[0];   // inputs_vector [2048, 50000]
  const float* W     = (const float*)d_in[1];   // W [256, 50000]
  const float* cls_w = (const float*)d_in[2];   // [49999, 256]
  const int* nodes   = (const int*)d_in[3];     // [2048, 32]
  const int* codes   = (const int*)d_in[4];     // [2048, 32]
  const int* lens    = (const int*)d_in[5];     // [2048]
  float* out = (float*)d_out;

  char* ws = (char*)d_ws;
  const size_t XBYTES = (size_t)M_DIM * N_DIM * sizeof(float);   // 2 MB
  float* per_sample = (float*)ws;                                // 8 KB
  float* x          = (float*)(ws + (size_t)(64u << 10));        // 2 MB (atomic path)
  float* partials   = (float*)(ws + (size_t)(4u << 20));         // KSPLIT * 2 MB

  int use_atomic = (ws_size < (size_t)(4u << 20) + (size_t)KSPLIT * XBYTES) ? 1 : 0;

  if (use_atomic) {
    hipMemsetAsync(x, 0, XBYTES, stream);
    gemm_bf16_splitk<<<dim3(MTILES * KSPLIT), dim3(512), 0, stream>>>(A, W, x, 1);
    loss_kernel<<<dim3(M_DIM), dim3(256), 0, stream>>>(x, 1, cls_w, nodes, codes, lens, per_sample);
  } else {
    gemm_bf16_splitk<<<dim3(MTILES * KSPLIT), dim3(512), 0, stream>>>(A, W, partials, 0);
    loss_kernel<<<dim3(M_DIM), dim3(256), 0, stream>>>(partials, KSPLIT, cls_w, nodes, codes, lens, per_sample);
  }
  final_reduce<<<dim3(1), dim3(256), 0, stream>>>(per_sample, out);
}